// Round 1
// baseline (1088.883 us; speedup 1.0000x reference)
//
#include <hip/hip_runtime.h>
#include <cstdint>

#define DD 128

// ---------------------------------------------------------------------------
// Detect whether edge_index arrived as int64 (reference dtype) or int32
// (JAX x64-disabled). int32 data misread as int64 gives values >= 2^32
// almost surely within 4096 samples. flag=1 -> int32, flag=0 -> int64.
// ---------------------------------------------------------------------------
__global__ __launch_bounds__(256) void detect_kernel(const void* ei, int E, int* flag) {
    const long long* p = (const long long*)ei;
    int n = E < 4096 ? E : 4096;   // safe either way: int32 layout has E int64-slots
    int bad = 0;
    for (int i = threadIdx.x; i < n; i += 256) {
        long long v = p[i];
        if (v < 0 || v >= (1LL << 32)) bad = 1;
    }
    __shared__ int s_bad;
    if (threadIdx.x == 0) s_bad = 0;
    __syncthreads();
    if (bad) atomicOr(&s_bad, 1);
    __syncthreads();
    if (threadIdx.x == 0) *flag = s_bad;
}

__global__ __launch_bounds__(256) void init_deg(int* deg, int N) {
    int i = blockIdx.x * 256 + threadIdx.x;
    if (i < N) deg[i] = 1;   // self-loop
}

// Normalize edges to int32 src/dst arrays + count destination degrees.
__global__ __launch_bounds__(256) void convert_count(const void* ei, int E, const int* flag,
                                                     int* src, int* dst, int* deg) {
    int e = blockIdx.x * 256 + threadIdx.x;
    if (e >= E) return;
    int s, t;
    if (*flag) {
        const int* p = (const int*)ei;
        s = p[e]; t = p[E + e];
    } else {
        const long long* p = (const long long*)ei;
        s = (int)p[e]; t = (int)p[E + e];
    }
    src[e] = s; dst[e] = t;
    atomicAdd(&deg[t], 1);
}

__global__ __launch_bounds__(256) void dis_kernel(const int* deg, float* dis, int N) {
    int i = blockIdx.x * 256 + threadIdx.x;
    if (i < N) dis[i] = rsqrtf((float)deg[i]);
}

// ---------------------------------------------------------------------------
// xw = x @ W  (f32, K=128, 128 cols), fused epilogue:
//   out = x + b + xw * dis^2   (residual + bias + self-loop message)
// Block: 256 threads, 32 rows. W staged in LDS in two 64-k halves (32 KB),
// x tile in LDS (padded). Thread (rr=tid/32, cc=tid%32) computes a 4x4 block:
// rows rr*4..+3, cols cc*4..+3.
// ---------------------------------------------------------------------------
__global__ __launch_bounds__(256) void gemm_fused(const float* __restrict__ x,
                                                  const float* __restrict__ W,
                                                  const float* __restrict__ b,
                                                  const float* __restrict__ dis,
                                                  float* __restrict__ xw,
                                                  float* __restrict__ out, int N) {
    __shared__ float sW[64 * 128];       // 32 KB: one k-half of W
    __shared__ float sx[32][132];        // 16.9 KB, +4 pad
    const int tid = threadIdx.x;
    const int row0 = blockIdx.x * 32;

    const float4* x4 = (const float4*)x;
    for (int i = tid; i < 32 * 32; i += 256) {   // 32 rows x 32 float4
        int r = i >> 5, c = i & 31;
        float4 v = make_float4(0.f, 0.f, 0.f, 0.f);
        if (row0 + r < N) v = x4[(size_t)(row0 + r) * 32 + c];
        *(float4*)&sx[r][c * 4] = v;
    }

    const int cc = tid & 31;    // col group: cols cc*4..+3
    const int rr = tid >> 5;    // row group: rows rr*4..+3
    float acc[4][4];
#pragma unroll
    for (int j = 0; j < 4; ++j)
#pragma unroll
        for (int i2 = 0; i2 < 4; ++i2) acc[j][i2] = 0.f;

    const float4* W4 = (const float4*)W;
    float4* sW4 = (float4*)sW;

    for (int half = 0; half < 2; ++half) {
        if (half) __syncthreads();                 // compute done before overwrite
        for (int i = tid; i < 64 * 32; i += 256)   // 64 k-rows x 32 float4
            sW4[i] = W4[half * 2048 + i];
        __syncthreads();

#pragma unroll 4
        for (int kq = 0; kq < 16; ++kq) {          // 4 k's per iter
            float xk[4][4];
#pragma unroll
            for (int j = 0; j < 4; ++j) {
                float4 xv = *(const float4*)&sx[rr * 4 + j][half * 64 + kq * 4];
                xk[j][0] = xv.x; xk[j][1] = xv.y; xk[j][2] = xv.z; xk[j][3] = xv.w;
            }
#pragma unroll
            for (int kk = 0; kk < 4; ++kk) {
                float4 w = *(const float4*)&sW[(kq * 4 + kk) * 128 + cc * 4];
#pragma unroll
                for (int j = 0; j < 4; ++j) {
                    acc[j][0] += xk[j][kk] * w.x;
                    acc[j][1] += xk[j][kk] * w.y;
                    acc[j][2] += xk[j][kk] * w.z;
                    acc[j][3] += xk[j][kk] * w.w;
                }
            }
        }
    }

    const float4 bv = ((const float4*)b)[cc];
    float4* xw4 = (float4*)xw;
    float4* out4 = (float4*)out;
#pragma unroll
    for (int j = 0; j < 4; ++j) {
        int grow = row0 + rr * 4 + j;
        if (grow < N) {
            float ds = dis[grow];
            float inv = ds * ds;                 // self-loop norm = 1/deg
            float4 a;
            a.x = acc[j][0]; a.y = acc[j][1]; a.z = acc[j][2]; a.w = acc[j][3];
            size_t off = (size_t)grow * 32 + cc;
            xw4[off] = a;
            float4 xv = x4[off];
            float4 o;
            o.x = xv.x + bv.x + a.x * inv;
            o.y = xv.y + bv.y + a.y * inv;
            o.z = xv.z + bv.z + a.z * inv;
            o.w = xv.w + bv.w + a.w * inv;
            out4[off] = o;
        }
    }
}

// ---------------------------------------------------------------------------
// Edge scatter: out[dst] += xw[src] * dis[src]*dis[dst]
// 32 lanes per edge, float4 gather, 4 f32 hw atomics per lane.
// ---------------------------------------------------------------------------
__global__ __launch_bounds__(256) void scatter_kernel(const float* __restrict__ xw,
                                                      const float* __restrict__ dis,
                                                      const int* __restrict__ src,
                                                      const int* __restrict__ dst,
                                                      float* __restrict__ out, int E) {
    int eg = blockIdx.x * 8 + (threadIdx.x >> 5);
    if (eg >= E) return;
    int lane4 = (threadIdx.x & 31) * 4;
    int s = src[eg], t = dst[eg];
    float norm = dis[s] * dis[t];
    float4 v = *(const float4*)&xw[(size_t)s * DD + lane4];
    float* o = &out[(size_t)t * DD + lane4];
    unsafeAtomicAdd(o + 0, v.x * norm);
    unsafeAtomicAdd(o + 1, v.y * norm);
    unsafeAtomicAdd(o + 2, v.z * norm);
    unsafeAtomicAdd(o + 3, v.w * norm);
}

extern "C" void kernel_launch(void* const* d_in, const int* in_sizes, int n_in,
                              void* d_out, int out_size, void* d_ws, size_t ws_size,
                              hipStream_t stream) {
    const float* x  = (const float*)d_in[0];
    const void*  ei = d_in[1];
    const float* W  = (const float*)d_in[2];
    const float* b  = (const float*)d_in[3];
    float* out = (float*)d_out;

    const int N = in_sizes[0] / DD;
    const int E = in_sizes[1] / 2;

    // Workspace layout (needs ~31 MB): flag | src | dst | deg | dis | xw
    char* ws = (char*)d_ws;
    int* flag = (int*)ws;
    int* src  = (int*)(ws + 256);
    int* dst  = src + E;
    int* deg  = dst + E;
    float* dis = (float*)(deg + N);
    size_t off = 256 + (size_t)E * 8 + (size_t)N * 8;
    off = (off + 255) & ~(size_t)255;
    float* xw = (float*)(ws + off);

    detect_kernel<<<1, 256, 0, stream>>>(ei, E, flag);
    init_deg<<<(N + 255) / 256, 256, 0, stream>>>(deg, N);
    convert_count<<<(E + 255) / 256, 256, 0, stream>>>(ei, E, flag, src, dst, deg);
    dis_kernel<<<(N + 255) / 256, 256, 0, stream>>>(deg, dis, N);
    gemm_fused<<<(N + 31) / 32, 256, 0, stream>>>(x, W, b, dis, xw, out, N);
    scatter_kernel<<<(E + 7) / 8, 256, 0, stream>>>(xw, dis, src, dst, out, E);
}

// Round 2
// 267.736 us; speedup vs baseline: 4.0670x; 4.0670x over previous
//
#include <hip/hip_runtime.h>
#include <cstdint>

#define DD 128

// ---------------------------------------------------------------------------
// Detect whether edge_index arrived as int64 (reference dtype) or int32
// (JAX x64-disabled). int32 data misread as int64 gives values >= 2^32
// almost surely within 4096 samples. flag=1 -> int32, flag=0 -> int64.
// ---------------------------------------------------------------------------
__global__ __launch_bounds__(256) void detect_kernel(const void* ei, int E, int* flag) {
    const long long* p = (const long long*)ei;
    int n = E < 4096 ? E : 4096;
    int bad = 0;
    for (int i = threadIdx.x; i < n; i += 256) {
        long long v = p[i];
        if (v < 0 || v >= (1LL << 32)) bad = 1;
    }
    __shared__ int s_bad;
    if (threadIdx.x == 0) s_bad = 0;
    __syncthreads();
    if (bad) atomicOr(&s_bad, 1);
    __syncthreads();
    if (threadIdx.x == 0) *flag = s_bad;
}

__device__ __forceinline__ int load_idx(const void* ei, int flag, long long pos) {
    if (flag) return ((const int*)ei)[pos];
    return (int)((const long long*)ei)[pos];
}

// Count incoming edges per destination node (self-loop NOT included in cnt).
__global__ __launch_bounds__(256) void count_kernel(const void* ei, int E, const int* flag,
                                                    int* cnt) {
    int e = blockIdx.x * 256 + threadIdx.x;
    if (e >= E) return;
    int t = load_idx(ei, *flag, (long long)E + e);
    atomicAdd(&cnt[t], 1);
}

__global__ __launch_bounds__(256) void dis_kernel(const int* cnt, float* dis, int N) {
    int i = blockIdx.x * 256 + threadIdx.x;
    if (i < N) dis[i] = rsqrtf((float)(cnt[i] + 1));   // +1 self-loop
}

// Single-block exclusive scan of cnt -> row_ptr[N+1]; also seeds cursor.
__global__ __launch_bounds__(1024) void scan_kernel(const int* __restrict__ cnt, int N,
                                                    int* __restrict__ row_ptr,
                                                    int* __restrict__ cursor) {
    __shared__ int s[1024];
    const int tid = threadIdx.x;
    const int chunk = (N + 1023) >> 10;
    int start = tid * chunk;
    int end = start + chunk; if (end > N) end = N;
    int lsum = 0;
    for (int i = start; i < end; ++i) lsum += cnt[i];
    s[tid] = lsum;
    __syncthreads();
    for (int off = 1; off < 1024; off <<= 1) {
        int v = (tid >= off) ? s[tid - off] : 0;
        __syncthreads();
        s[tid] += v;
        __syncthreads();
    }
    int prefix = (tid == 0) ? 0 : s[tid - 1];
    for (int i = start; i < end; ++i) {
        row_ptr[i] = prefix;
        cursor[i]  = prefix;
        prefix += cnt[i];
    }
    if (tid == 0) row_ptr[N] = s[1023];
}

// Bucket-fill: col[pos] = src for each edge, pos allocated per-dst cursor.
__global__ __launch_bounds__(256) void fill_kernel(const void* ei, int E, const int* flag,
                                                   int* cursor, int* col) {
    int e = blockIdx.x * 256 + threadIdx.x;
    if (e >= E) return;
    int f = *flag;
    int s = load_idx(ei, f, e);
    int t = load_idx(ei, f, (long long)E + e);
    int pos = atomicAdd(&cursor[t], 1);
    col[pos] = s;
}

// ---------------------------------------------------------------------------
// xws = (x @ W) * dis[row]   (f32 vector GEMM, K=128, 128 cols)
// Block: 256 threads, 32 rows; W staged in LDS in two 64-k halves.
// ---------------------------------------------------------------------------
__global__ __launch_bounds__(256) void gemm_xws(const float* __restrict__ x,
                                                const float* __restrict__ W,
                                                const float* __restrict__ dis,
                                                float* __restrict__ xws, int N) {
    __shared__ float sW[64 * 128];
    __shared__ float sx[32][132];
    const int tid = threadIdx.x;
    const int row0 = blockIdx.x * 32;

    const float4* x4 = (const float4*)x;
    for (int i = tid; i < 32 * 32; i += 256) {
        int r = i >> 5, c = i & 31;
        float4 v = make_float4(0.f, 0.f, 0.f, 0.f);
        if (row0 + r < N) v = x4[(size_t)(row0 + r) * 32 + c];
        *(float4*)&sx[r][c * 4] = v;
    }

    const int cc = tid & 31;
    const int rr = tid >> 5;
    float acc[4][4];
#pragma unroll
    for (int j = 0; j < 4; ++j)
#pragma unroll
        for (int i2 = 0; i2 < 4; ++i2) acc[j][i2] = 0.f;

    const float4* W4 = (const float4*)W;
    float4* sW4 = (float4*)sW;

    for (int half = 0; half < 2; ++half) {
        if (half) __syncthreads();
        for (int i = tid; i < 64 * 32; i += 256)
            sW4[i] = W4[half * 2048 + i];
        __syncthreads();

#pragma unroll 4
        for (int kq = 0; kq < 16; ++kq) {
            float xk[4][4];
#pragma unroll
            for (int j = 0; j < 4; ++j) {
                float4 xv = *(const float4*)&sx[rr * 4 + j][half * 64 + kq * 4];
                xk[j][0] = xv.x; xk[j][1] = xv.y; xk[j][2] = xv.z; xk[j][3] = xv.w;
            }
#pragma unroll
            for (int kk = 0; kk < 4; ++kk) {
                float4 w = *(const float4*)&sW[(kq * 4 + kk) * 128 + cc * 4];
#pragma unroll
                for (int j = 0; j < 4; ++j) {
                    acc[j][0] += xk[j][kk] * w.x;
                    acc[j][1] += xk[j][kk] * w.y;
                    acc[j][2] += xk[j][kk] * w.z;
                    acc[j][3] += xk[j][kk] * w.w;
                }
            }
        }
    }

    float4* xws4 = (float4*)xws;
#pragma unroll
    for (int j = 0; j < 4; ++j) {
        int grow = row0 + rr * 4 + j;
        if (grow < N) {
            float ds = dis[grow];
            float4 a;
            a.x = acc[j][0] * ds; a.y = acc[j][1] * ds;
            a.z = acc[j][2] * ds; a.w = acc[j][3] * ds;
            xws4[(size_t)grow * 32 + cc] = a;
        }
    }
}

// ---------------------------------------------------------------------------
// Pull-gather: out[t] = x[t] + b + dis[t] * (xws[t] + sum_{e in CSR[t]} xws[col_e])
// Half-wave (32 lanes, float4/lane) per node. No float atomics anywhere.
// ---------------------------------------------------------------------------
__global__ __launch_bounds__(256) void gather_kernel(const float* __restrict__ xws,
                                                     const float* __restrict__ x,
                                                     const float* __restrict__ b,
                                                     const float* __restrict__ dis,
                                                     const int* __restrict__ row_ptr,
                                                     const int* __restrict__ col,
                                                     float* __restrict__ out, int N) {
    int node = blockIdx.x * 8 + (threadIdx.x >> 5);
    if (node >= N) return;
    const int lane = threadIdx.x & 31;
    const float4* xws4 = (const float4*)xws;
    const size_t base = (size_t)node * 32 + lane;

    float4 acc = xws4[base];                     // self-loop term (pre-scaled)
    const int beg = row_ptr[node], end = row_ptr[node + 1];
    for (int i = beg; i < end; ++i) {
        int s = col[i];
        float4 v = xws4[(size_t)s * 32 + lane];
        acc.x += v.x; acc.y += v.y; acc.z += v.z; acc.w += v.w;
    }

    float d = dis[node];
    float4 xv = ((const float4*)x)[base];
    float4 bv = ((const float4*)b)[lane];
    float4 o;
    o.x = xv.x + bv.x + d * acc.x;
    o.y = xv.y + bv.y + d * acc.y;
    o.z = xv.z + bv.z + d * acc.z;
    o.w = xv.w + bv.w + d * acc.w;
    ((float4*)out)[base] = o;
}

extern "C" void kernel_launch(void* const* d_in, const int* in_sizes, int n_in,
                              void* d_out, int out_size, void* d_ws, size_t ws_size,
                              hipStream_t stream) {
    const float* x  = (const float*)d_in[0];
    const void*  ei = d_in[1];
    const float* W  = (const float*)d_in[2];
    const float* b  = (const float*)d_in[3];
    float* out = (float*)d_out;

    const int N = in_sizes[0] / DD;
    const int E = in_sizes[1] / 2;

    // Workspace layout (~28.8 MB): flag | cnt | dis | row_ptr | cursor | col | xws
    char* ws = (char*)d_ws;
    int*   flag    = (int*)ws;
    int*   cnt     = (int*)(ws + 256);
    float* dis     = (float*)(cnt + N);
    int*   row_ptr = (int*)(dis + N);
    int*   cursor  = row_ptr + (N + 1);
    int*   col     = cursor + N;
    size_t off = 256 + (size_t)N * 4 * 4 + 4 + (size_t)E * 4;
    off = (off + 255) & ~(size_t)255;
    float* xws = (float*)(ws + off);

    detect_kernel<<<1, 256, 0, stream>>>(ei, E, flag);
    hipMemsetAsync(cnt, 0, (size_t)N * 4, stream);
    count_kernel<<<(E + 255) / 256, 256, 0, stream>>>(ei, E, flag, cnt);
    dis_kernel<<<(N + 255) / 256, 256, 0, stream>>>(cnt, dis, N);
    gemm_xws<<<(N + 31) / 32, 256, 0, stream>>>(x, W, dis, xws, N);
    scan_kernel<<<1, 1024, 0, stream>>>(cnt, N, row_ptr, cursor);
    fill_kernel<<<(E + 255) / 256, 256, 0, stream>>>(ei, E, flag, cursor, col);
    gather_kernel<<<(N + 7) / 8, 256, 0, stream>>>(xws, x, b, dis, row_ptr, col, out, N);
}

// Round 3
// 167.913 us; speedup vs baseline: 6.4848x; 1.5945x over previous
//
#include <hip/hip_runtime.h>
#include <cstdint>

#define DD 128
#define SB 128   // scan blocks

// ---------------------------------------------------------------------------
// Detect whether edge_index arrived as int64 (reference dtype) or int32
// (JAX x64-disabled). int32 data misread as int64 gives values >= 2^32 with
// prob ~1 per slot (hi word is a random node id; ==0 with p=2e-5).
// flag=1 -> int32, flag=0 -> int64.
// ---------------------------------------------------------------------------
__global__ __launch_bounds__(256) void detect_kernel(const void* ei, int E, int* flag) {
    const long long* p = (const long long*)ei;
    int n = E < 2048 ? E : 2048;
    int bad = 0;
    for (int i = threadIdx.x; i < n; i += 256) {
        long long v = p[i];
        if (v < 0 || v >= (1LL << 32)) bad = 1;
    }
    __shared__ int s_bad;
    if (threadIdx.x == 0) s_bad = 0;
    __syncthreads();
    if (bad) atomicOr(&s_bad, 1);
    __syncthreads();
    if (threadIdx.x == 0) *flag = s_bad;
}

__device__ __forceinline__ int load_idx(const void* ei, int flag, long long pos) {
    if (flag) return ((const int*)ei)[pos];
    return (int)((const long long*)ei)[pos];
}

// Count incoming edges per destination node (self-loop NOT included in cnt).
__global__ __launch_bounds__(256) void count_kernel(const void* ei, int E, const int* flag,
                                                    int* cnt) {
    int e = blockIdx.x * 256 + threadIdx.x;
    if (e >= E) return;
    int t = load_idx(ei, *flag, (long long)E + e);
    atomicAdd(&cnt[t], 1);
}

// ---------------------------------------------------------------------------
// Multi-block exclusive scan of cnt[N] -> row_ptr/cursor, fused dis.
// ---------------------------------------------------------------------------
__global__ __launch_bounds__(256) void scan_part(const int* __restrict__ cnt, int N,
                                                 int* __restrict__ bsum) {
    const int ch = (N + SB - 1) / SB;
    const int beg = blockIdx.x * ch;
    const int end = min(beg + ch, N);
    int lsum = 0;
    for (int i = beg + threadIdx.x; i < end; i += 256) lsum += cnt[i];
    __shared__ int s[256];
    s[threadIdx.x] = lsum;
    __syncthreads();
    for (int off = 128; off > 0; off >>= 1) {
        if (threadIdx.x < off) s[threadIdx.x] += s[threadIdx.x + off];
        __syncthreads();
    }
    if (threadIdx.x == 0) bsum[blockIdx.x] = s[0];
}

__global__ __launch_bounds__(SB) void scan_mid(const int* __restrict__ bsum,
                                               int* __restrict__ bbase,
                                               int* __restrict__ row_ptr, int N) {
    __shared__ int s[SB];
    int tid = threadIdx.x;
    s[tid] = bsum[tid];
    __syncthreads();
    for (int off = 1; off < SB; off <<= 1) {
        int v = (tid >= off) ? s[tid - off] : 0;
        __syncthreads();
        s[tid] += v;
        __syncthreads();
    }
    bbase[tid] = (tid == 0) ? 0 : s[tid - 1];
    if (tid == SB - 1) row_ptr[N] = s[SB - 1];
}

__global__ __launch_bounds__(256) void scan_final(const int* __restrict__ cnt, int N,
                                                  const int* __restrict__ bbase,
                                                  int* __restrict__ row_ptr,
                                                  int* __restrict__ cursor,
                                                  float* __restrict__ dis) {
    const int ch = (N + SB - 1) / SB;             // elems per block
    const int tch = (ch + 255) / 256;             // elems per thread (contiguous)
    const int beg = blockIdx.x * ch;
    const int tid = threadIdx.x;

    // per-thread local sum of its contiguous sub-chunk
    int tbeg = beg + tid * tch;
    int tend = min(tbeg + tch, min(beg + ch, N));
    int lsum = 0;
    for (int i = tbeg; i < tend; ++i) lsum += cnt[i];

    __shared__ int s[256];
    s[tid] = lsum;
    __syncthreads();
    for (int off = 1; off < 256; off <<= 1) {
        int v = (tid >= off) ? s[tid - off] : 0;
        __syncthreads();
        s[tid] += v;
        __syncthreads();
    }
    int prefix = bbase[blockIdx.x] + ((tid == 0) ? 0 : s[tid - 1]);
    for (int i = tbeg; i < tend; ++i) {
        int c = cnt[i];
        row_ptr[i] = prefix;
        cursor[i]  = prefix;
        dis[i] = rsqrtf((float)(c + 1));          // +1 self-loop
        prefix += c;
    }
}

// Bucket-fill: col[pos] = src for each edge, pos allocated per-dst cursor.
__global__ __launch_bounds__(256) void fill_kernel(const void* ei, int E, const int* flag,
                                                   int* cursor, int* col) {
    int e = blockIdx.x * 256 + threadIdx.x;
    if (e >= E) return;
    int f = *flag;
    int s = load_idx(ei, f, e);
    int t = load_idx(ei, f, (long long)E + e);
    int pos = atomicAdd(&cursor[t], 1);
    col[pos] = s;
}

// ---------------------------------------------------------------------------
// xws = (x @ W) * dis[row]   (f32 vector GEMM, K=128, 128 cols)
// ---------------------------------------------------------------------------
__global__ __launch_bounds__(256) void gemm_xws(const float* __restrict__ x,
                                                const float* __restrict__ W,
                                                const float* __restrict__ dis,
                                                float* __restrict__ xws, int N) {
    __shared__ float sW[64 * 128];
    __shared__ float sx[32][132];
    const int tid = threadIdx.x;
    const int row0 = blockIdx.x * 32;

    const float4* x4 = (const float4*)x;
    for (int i = tid; i < 32 * 32; i += 256) {
        int r = i >> 5, c = i & 31;
        float4 v = make_float4(0.f, 0.f, 0.f, 0.f);
        if (row0 + r < N) v = x4[(size_t)(row0 + r) * 32 + c];
        *(float4*)&sx[r][c * 4] = v;
    }

    const int cc = tid & 31;
    const int rr = tid >> 5;
    float acc[4][4];
#pragma unroll
    for (int j = 0; j < 4; ++j)
#pragma unroll
        for (int i2 = 0; i2 < 4; ++i2) acc[j][i2] = 0.f;

    const float4* W4 = (const float4*)W;
    float4* sW4 = (float4*)sW;

    for (int half = 0; half < 2; ++half) {
        if (half) __syncthreads();
        for (int i = tid; i < 64 * 32; i += 256)
            sW4[i] = W4[half * 2048 + i];
        __syncthreads();

#pragma unroll 4
        for (int kq = 0; kq < 16; ++kq) {
            float xk[4][4];
#pragma unroll
            for (int j = 0; j < 4; ++j) {
                float4 xv = *(const float4*)&sx[rr * 4 + j][half * 64 + kq * 4];
                xk[j][0] = xv.x; xk[j][1] = xv.y; xk[j][2] = xv.z; xk[j][3] = xv.w;
            }
#pragma unroll
            for (int kk = 0; kk < 4; ++kk) {
                float4 w = *(const float4*)&sW[(kq * 4 + kk) * 128 + cc * 4];
#pragma unroll
                for (int j = 0; j < 4; ++j) {
                    acc[j][0] += xk[j][kk] * w.x;
                    acc[j][1] += xk[j][kk] * w.y;
                    acc[j][2] += xk[j][kk] * w.z;
                    acc[j][3] += xk[j][kk] * w.w;
                }
            }
        }
    }

    float4* xws4 = (float4*)xws;
#pragma unroll
    for (int j = 0; j < 4; ++j) {
        int grow = row0 + rr * 4 + j;
        if (grow < N) {
            float ds = dis[grow];
            float4 a;
            a.x = acc[j][0] * ds; a.y = acc[j][1] * ds;
            a.z = acc[j][2] * ds; a.w = acc[j][3] * ds;
            xws4[(size_t)grow * 32 + cc] = a;
        }
    }
}

// ---------------------------------------------------------------------------
// Pull-gather: out[t] = x[t] + b + dis[t] * (xws[t] + sum_{e in CSR[t]} xws[col_e])
// Half-wave (32 lanes, float4/lane) per node. No float atomics anywhere.
// ---------------------------------------------------------------------------
__global__ __launch_bounds__(256) void gather_kernel(const float* __restrict__ xws,
                                                     const float* __restrict__ x,
                                                     const float* __restrict__ b,
                                                     const float* __restrict__ dis,
                                                     const int* __restrict__ row_ptr,
                                                     const int* __restrict__ col,
                                                     float* __restrict__ out, int N) {
    int node = blockIdx.x * 8 + (threadIdx.x >> 5);
    if (node >= N) return;
    const int lane = threadIdx.x & 31;
    const float4* xws4 = (const float4*)xws;
    const size_t base = (size_t)node * 32 + lane;

    float4 acc = xws4[base];                     // self-loop term (pre-scaled)
    const int beg = row_ptr[node], end = row_ptr[node + 1];
    for (int i = beg; i < end; ++i) {
        int s = col[i];
        float4 v = xws4[(size_t)s * 32 + lane];
        acc.x += v.x; acc.y += v.y; acc.z += v.z; acc.w += v.w;
    }

    float d = dis[node];
    float4 xv = ((const float4*)x)[base];
    float4 bv = ((const float4*)b)[lane];
    float4 o;
    o.x = xv.x + bv.x + d * acc.x;
    o.y = xv.y + bv.y + d * acc.y;
    o.z = xv.z + bv.z + d * acc.z;
    o.w = xv.w + bv.w + d * acc.w;
    ((float4*)out)[base] = o;
}

extern "C" void kernel_launch(void* const* d_in, const int* in_sizes, int n_in,
                              void* d_out, int out_size, void* d_ws, size_t ws_size,
                              hipStream_t stream) {
    const float* x  = (const float*)d_in[0];
    const void*  ei = d_in[1];
    const float* W  = (const float*)d_in[2];
    const float* b  = (const float*)d_in[3];
    float* out = (float*)d_out;

    const int N = in_sizes[0] / DD;
    const int E = in_sizes[1] / 2;

    // Workspace: flag | bsum | bbase | cnt | dis | row_ptr | cursor | col | xws
    char* ws = (char*)d_ws;
    int*   flag    = (int*)ws;
    int*   bsum    = (int*)(ws + 256);
    int*   bbase   = bsum + SB;
    int*   cnt     = bbase + SB;
    float* dis     = (float*)(cnt + N);
    int*   row_ptr = (int*)(dis + N);
    int*   cursor  = row_ptr + (N + 1);
    int*   col     = cursor + N;
    size_t off = 256 + (size_t)SB * 8 + (size_t)N * 16 + 4 + (size_t)E * 4;
    off = (off + 255) & ~(size_t)255;
    float* xws = (float*)(ws + off);

    detect_kernel<<<1, 256, 0, stream>>>(ei, E, flag);
    hipMemsetAsync(cnt, 0, (size_t)N * 4, stream);
    count_kernel<<<(E + 255) / 256, 256, 0, stream>>>(ei, E, flag, cnt);
    scan_part<<<SB, 256, 0, stream>>>(cnt, N, bsum);
    scan_mid<<<1, SB, 0, stream>>>(bsum, bbase, row_ptr, N);
    scan_final<<<SB, 256, 0, stream>>>(cnt, N, bbase, row_ptr, cursor, dis);
    gemm_xws<<<(N + 31) / 32, 256, 0, stream>>>(x, W, dis, xws, N);
    fill_kernel<<<(E + 255) / 256, 256, 0, stream>>>(ei, E, flag, cursor, col);
    gather_kernel<<<(N + 7) / 8, 256, 0, stream>>>(xws, x, b, dis, row_ptr, col, out, N);
}

// Round 4
// 149.738 us; speedup vs baseline: 7.2719x; 1.1214x over previous
//
#include <hip/hip_runtime.h>
#include <cstdint>

#define DD 128
#define SB 128   // scan blocks

typedef __attribute__((ext_vector_type(8))) short bf16x8;
typedef __attribute__((ext_vector_type(4))) float f32x4;

__device__ __forceinline__ short f2bf(float f) {
    union { float f; unsigned u; } v; v.f = f;
    unsigned r = v.u + 0x7FFFu + ((v.u >> 16) & 1u);   // RNE
    return (short)(r >> 16);
}
__device__ __forceinline__ float bf2f(unsigned short s) {
    union { unsigned u; float f; } v; v.u = ((unsigned)s) << 16;
    return v.f;
}

__device__ __forceinline__ int load_idx(const void* ei, int flag, long long pos) {
    if (flag) return ((const int*)ei)[pos];
    return (int)((const long long*)ei)[pos];
}

// ---------------------------------------------------------------------------
// Merged detect+count. Each block redundantly detects int32-vs-int64 from the
// first 2048 int64-slots (16 KB, L2-hot), then counts dst degrees.
// flag=1 -> int32, flag=0 -> int64. Block 0 publishes flag for fill_kernel.
// ---------------------------------------------------------------------------
__global__ __launch_bounds__(256) void count_kernel(const void* ei, int E,
                                                    int* flag_out, int* cnt) {
    __shared__ int s_flag;
    if (threadIdx.x == 0) s_flag = 0;
    __syncthreads();
    const long long* p = (const long long*)ei;
    int n = E < 2048 ? E : 2048;
    int bad = 0;
    for (int i = threadIdx.x; i < n; i += 256) {
        long long v = p[i];
        if (v < 0 || v >= (1LL << 32)) bad = 1;
    }
    if (bad) atomicOr(&s_flag, 1);
    __syncthreads();
    const int f = s_flag;
    if (blockIdx.x == 0 && threadIdx.x == 0) *flag_out = f;

    int e = blockIdx.x * 256 + threadIdx.x;
    if (e < E) {
        int t = load_idx(ei, f, (long long)E + e);
        atomicAdd(&cnt[t], 1);
    }
}

// ---------------------------------------------------------------------------
// Multi-block exclusive scan of cnt[N] -> row_ptr/cursor, fused dis.
// ---------------------------------------------------------------------------
__global__ __launch_bounds__(256) void scan_part(const int* __restrict__ cnt, int N,
                                                 int* __restrict__ bsum) {
    const int ch = (N + SB - 1) / SB;
    const int beg = blockIdx.x * ch;
    const int end = min(beg + ch, N);
    int lsum = 0;
    for (int i = beg + threadIdx.x; i < end; i += 256) lsum += cnt[i];
    __shared__ int s[256];
    s[threadIdx.x] = lsum;
    __syncthreads();
    for (int off = 128; off > 0; off >>= 1) {
        if (threadIdx.x < off) s[threadIdx.x] += s[threadIdx.x + off];
        __syncthreads();
    }
    if (threadIdx.x == 0) bsum[blockIdx.x] = s[0];
}

__global__ __launch_bounds__(SB) void scan_mid(const int* __restrict__ bsum,
                                               int* __restrict__ bbase,
                                               int* __restrict__ row_ptr, int N) {
    __shared__ int s[SB];
    int tid = threadIdx.x;
    s[tid] = bsum[tid];
    __syncthreads();
    for (int off = 1; off < SB; off <<= 1) {
        int v = (tid >= off) ? s[tid - off] : 0;
        __syncthreads();
        s[tid] += v;
        __syncthreads();
    }
    bbase[tid] = (tid == 0) ? 0 : s[tid - 1];
    if (tid == SB - 1) row_ptr[N] = s[SB - 1];
}

__global__ __launch_bounds__(256) void scan_final(const int* __restrict__ cnt, int N,
                                                  const int* __restrict__ bbase,
                                                  int* __restrict__ row_ptr,
                                                  int* __restrict__ cursor,
                                                  float* __restrict__ dis) {
    const int ch = (N + SB - 1) / SB;
    const int tch = (ch + 255) / 256;
    const int beg = blockIdx.x * ch;
    const int tid = threadIdx.x;

    int tbeg = beg + tid * tch;
    int tend = min(tbeg + tch, min(beg + ch, N));
    int lsum = 0;
    for (int i = tbeg; i < tend; ++i) lsum += cnt[i];

    __shared__ int s[256];
    s[tid] = lsum;
    __syncthreads();
    for (int off = 1; off < 256; off <<= 1) {
        int v = (tid >= off) ? s[tid - off] : 0;
        __syncthreads();
        s[tid] += v;
        __syncthreads();
    }
    int prefix = bbase[blockIdx.x] + ((tid == 0) ? 0 : s[tid - 1]);
    for (int i = tbeg; i < tend; ++i) {
        int c = cnt[i];
        row_ptr[i] = prefix;
        cursor[i]  = prefix;
        dis[i] = rsqrtf((float)(c + 1));   // +1 self-loop
        prefix += c;
    }
}

// Bucket-fill: col[pos] = src for each edge, pos allocated per-dst cursor.
__global__ __launch_bounds__(256) void fill_kernel(const void* ei, int E, const int* flag,
                                                   int* cursor, int* col) {
    int e = blockIdx.x * 256 + threadIdx.x;
    if (e >= E) return;
    int f = *flag;
    int s = load_idx(ei, f, e);
    int t = load_idx(ei, f, (long long)E + e);
    int pos = atomicAdd(&cursor[t], 1);
    col[pos] = s;
}

// Wp[n][k] = bf16(W[k][n])  (transposed so B-fragment lanes read 16B contiguous)
__global__ __launch_bounds__(256) void pack_w(const float* __restrict__ W,
                                              short* __restrict__ Wp) {
    const int i = blockIdx.x * 256 + threadIdx.x;   // 0..16383
    const int k = i >> 7, n = i & 127;
    Wp[n * DD + k] = f2bf(W[i]);
}

// ---------------------------------------------------------------------------
// xws[row] = bf16( (x[row] @ W) * dis[row] )  via mfma_f32_16x16x32_bf16.
// 4 waves/block, 16 rows/wave, 64 rows/block. A loaded direct from global f32
// (2x float4/lane, converted in-reg); B from packed Wp (L1/L2-resident).
// Fragment maps: A: m=lane%16, k=(lane/16)*8+e ; B: n=lane%16, same k;
// C/D: col=lane%16, row=(lane/16)*4+reg  [verified m89/m91].
// ---------------------------------------------------------------------------
__global__ __launch_bounds__(256) void gemm_mfma(const float* __restrict__ x,
                                                 const short* __restrict__ Wp,
                                                 const float* __restrict__ dis,
                                                 short* __restrict__ xws, int N) {
    const int tid = threadIdx.x;
    const int wave = tid >> 6;
    const int lane = tid & 63;
    const int lmod = lane & 15;
    const int lgrp = lane >> 4;
    const int rowbase = blockIdx.x * 64 + wave * 16;
    const int arow = rowbase + lmod;
    const bool aok = arow < N;

    f32x4 acc[8];
#pragma unroll
    for (int i = 0; i < 8; ++i) acc[i] = (f32x4){0.f, 0.f, 0.f, 0.f};

#pragma unroll
    for (int ks = 0; ks < 4; ++ks) {
        const int kbase = ks * 32 + lgrp * 8;
        bf16x8 afrag;
        if (aok) {
            const float4 a0 = *(const float4*)&x[(size_t)arow * DD + kbase];
            const float4 a1 = *(const float4*)&x[(size_t)arow * DD + kbase + 4];
            afrag[0] = f2bf(a0.x); afrag[1] = f2bf(a0.y);
            afrag[2] = f2bf(a0.z); afrag[3] = f2bf(a0.w);
            afrag[4] = f2bf(a1.x); afrag[5] = f2bf(a1.y);
            afrag[6] = f2bf(a1.z); afrag[7] = f2bf(a1.w);
        } else {
#pragma unroll
            for (int i = 0; i < 8; ++i) afrag[i] = 0;
        }
#pragma unroll
        for (int nt = 0; nt < 8; ++nt) {
            bf16x8 bfrag = *(const bf16x8*)&Wp[(nt * 16 + lmod) * DD + kbase];
            acc[nt] = __builtin_amdgcn_mfma_f32_16x16x32_bf16(afrag, bfrag, acc[nt], 0, 0, 0);
        }
    }

#pragma unroll
    for (int r = 0; r < 4; ++r) {
        const int row = rowbase + lgrp * 4 + r;
        if (row < N) {
            const float ds = dis[row];
#pragma unroll
            for (int nt = 0; nt < 8; ++nt)
                xws[(size_t)row * DD + nt * 16 + lmod] = f2bf(acc[nt][r] * ds);
        }
    }
}

// ---------------------------------------------------------------------------
// Pull-gather (bf16 rows): out[t] = x[t] + b + dis[t]*(xws[t] + sum xws[col_e])
// Half-wave per node, ushort4 (8B) per lane, f32 accumulate.
// ---------------------------------------------------------------------------
__global__ __launch_bounds__(256) void gather_kernel(const short* __restrict__ xws,
                                                     const float* __restrict__ x,
                                                     const float* __restrict__ b,
                                                     const float* __restrict__ dis,
                                                     const int* __restrict__ row_ptr,
                                                     const int* __restrict__ col,
                                                     float* __restrict__ out, int N) {
    const int node = blockIdx.x * 8 + (threadIdx.x >> 5);
    if (node >= N) return;
    const int lane = threadIdx.x & 31;
    const ushort4* xw4 = (const ushort4*)xws;
    const size_t base = (size_t)node * 32 + lane;

    ushort4 sv = xw4[base];                       // self-loop term (pre-scaled)
    float a0 = bf2f(sv.x), a1 = bf2f(sv.y), a2 = bf2f(sv.z), a3 = bf2f(sv.w);

    const int beg = row_ptr[node], end = row_ptr[node + 1];
    for (int i = beg; i < end; ++i) {
        const int s = col[i];
        ushort4 v = xw4[(size_t)s * 32 + lane];
        a0 += bf2f(v.x); a1 += bf2f(v.y); a2 += bf2f(v.z); a3 += bf2f(v.w);
    }

    const float d = dis[node];
    const float4 xv = ((const float4*)x)[base];
    const float4 bv = ((const float4*)b)[lane];
    float4 o;
    o.x = xv.x + bv.x + d * a0;
    o.y = xv.y + bv.y + d * a1;
    o.z = xv.z + bv.z + d * a2;
    o.w = xv.w + bv.w + d * a3;
    ((float4*)out)[base] = o;
}

extern "C" void kernel_launch(void* const* d_in, const int* in_sizes, int n_in,
                              void* d_out, int out_size, void* d_ws, size_t ws_size,
                              hipStream_t stream) {
    const float* x  = (const float*)d_in[0];
    const void*  ei = d_in[1];
    const float* W  = (const float*)d_in[2];
    const float* b  = (const float*)d_in[3];
    float* out = (float*)d_out;

    const int N = in_sizes[0] / DD;
    const int E = in_sizes[1] / 2;

    // Workspace: flag | bsum | bbase | cnt | dis | row_ptr | cursor | col | Wp | xws
    char* ws = (char*)d_ws;
    int*   flag    = (int*)ws;
    int*   bsum    = (int*)(ws + 256);
    int*   bbase   = bsum + SB;
    int*   cnt     = bbase + SB;
    float* dis     = (float*)(cnt + N);
    int*   row_ptr = (int*)(dis + N);
    int*   cursor  = row_ptr + (N + 1);
    int*   col     = cursor + N;
    size_t off = 256 + (size_t)SB * 8 + (size_t)N * 16 + 4 + (size_t)E * 4;
    off = (off + 255) & ~(size_t)255;
    short* Wp  = (short*)(ws + off);
    off += (size_t)DD * DD * 2;               // 32 KB, keeps 256 alignment
    short* xws = (short*)(ws + off);

    hipMemsetAsync(cnt, 0, (size_t)N * 4, stream);
    count_kernel<<<(E + 255) / 256, 256, 0, stream>>>(ei, E, flag, cnt);
    scan_part<<<SB, 256, 0, stream>>>(cnt, N, bsum);
    scan_mid<<<1, SB, 0, stream>>>(bsum, bbase, row_ptr, N);
    scan_final<<<SB, 256, 0, stream>>>(cnt, N, bbase, row_ptr, cursor, dis);
    pack_w<<<64, 256, 0, stream>>>(W, Wp);
    gemm_mfma<<<(N + 63) / 64, 256, 0, stream>>>(x, Wp, dis, xws, N);
    fill_kernel<<<(E + 255) / 256, 256, 0, stream>>>(ei, E, flag, cursor, col);
    gather_kernel<<<(N + 7) / 8, 256, 0, stream>>>(xws, x, b, dis, row_ptr, col, out, N);
}

// Round 5
// 131.058 us; speedup vs baseline: 8.3084x; 1.1425x over previous
//
#include <hip/hip_runtime.h>
#include <cstdint>

#define DD 128
#define SB 128   // scan blocks

typedef __attribute__((ext_vector_type(8))) short bf16x8;
typedef __attribute__((ext_vector_type(4))) float f32x4;

__device__ __forceinline__ short f2bf(float f) {
    union { float f; unsigned u; } v; v.f = f;
    unsigned r = v.u + 0x7FFFu + ((v.u >> 16) & 1u);   // RNE
    return (short)(r >> 16);
}
__device__ __forceinline__ float bf2f(unsigned short s) {
    union { unsigned u; float f; } v; v.u = ((unsigned)s) << 16;
    return v.f;
}

__device__ __forceinline__ int load_idx(const void* ei, int flag, long long pos) {
    if (flag) return ((const int*)ei)[pos];
    return (int)((const long long*)ei)[pos];
}

// ---------------------------------------------------------------------------
// Merged detect+count. Each block redundantly detects int32-vs-int64 from the
// first 256 int64-slots (L2-hot). A packed-int32 slot misreads as >=2^32
// unless its hi int32 is 0 (p = 2e-5); 256 slots -> miss prob ~0.
// flag=1 -> int32, flag=0 -> int64.
// ---------------------------------------------------------------------------
__global__ __launch_bounds__(256) void count_kernel(const void* ei, int E,
                                                    int* flag_out, int* cnt) {
    __shared__ int s_flag;
    if (threadIdx.x == 0) s_flag = 0;
    __syncthreads();
    const long long* p = (const long long*)ei;
    int n = E < 256 ? E : 256;
    int bad = 0;
    if (threadIdx.x < n) {
        long long v = p[threadIdx.x];
        if (v < 0 || v >= (1LL << 32)) bad = 1;
    }
    if (bad) atomicOr(&s_flag, 1);
    __syncthreads();
    const int f = s_flag;
    if (blockIdx.x == 0 && threadIdx.x == 0) *flag_out = f;

    int e = blockIdx.x * 256 + threadIdx.x;
    if (e < E) {
        int t = load_idx(ei, f, (long long)E + e);
        atomicAdd(&cnt[t], 1);
    }
}

// ---------------------------------------------------------------------------
// Multi-block exclusive scan of cnt[N] -> row_ptr/cursor, fused dis.
// scan_part also packs W -> Wp (bf16, transposed) with its spare threads.
// ---------------------------------------------------------------------------
__global__ __launch_bounds__(256) void scan_part(const int* __restrict__ cnt, int N,
                                                 int* __restrict__ bsum,
                                                 const float* __restrict__ W,
                                                 short* __restrict__ Wp) {
    // fused W pack: 16384 elems over first 64 blocks
    const int gi = blockIdx.x * 256 + threadIdx.x;
    if (gi < DD * DD) {
        const int k = gi >> 7, n = gi & 127;
        Wp[n * DD + k] = f2bf(W[gi]);
    }

    const int ch = (N + SB - 1) / SB;
    const int beg = blockIdx.x * ch;
    const int end = min(beg + ch, N);
    int lsum = 0;
    for (int i = beg + threadIdx.x; i < end; i += 256) lsum += cnt[i];
    __shared__ int s[256];
    s[threadIdx.x] = lsum;
    __syncthreads();
    for (int off = 128; off > 0; off >>= 1) {
        if (threadIdx.x < off) s[threadIdx.x] += s[threadIdx.x + off];
        __syncthreads();
    }
    if (threadIdx.x == 0) bsum[blockIdx.x] = s[0];
}

__global__ __launch_bounds__(SB) void scan_mid(const int* __restrict__ bsum,
                                               int* __restrict__ bbase,
                                               int* __restrict__ row_ptr, int N) {
    __shared__ int s[SB];
    int tid = threadIdx.x;
    s[tid] = bsum[tid];
    __syncthreads();
    for (int off = 1; off < SB; off <<= 1) {
        int v = (tid >= off) ? s[tid - off] : 0;
        __syncthreads();
        s[tid] += v;
        __syncthreads();
    }
    bbase[tid] = (tid == 0) ? 0 : s[tid - 1];
    if (tid == SB - 1) row_ptr[N] = s[SB - 1];
}

__global__ __launch_bounds__(256) void scan_final(const int* __restrict__ cnt, int N,
                                                  const int* __restrict__ bbase,
                                                  int* __restrict__ row_ptr,
                                                  int* __restrict__ cursor,
                                                  float* __restrict__ dis) {
    const int ch = (N + SB - 1) / SB;
    const int tch = (ch + 255) / 256;
    const int beg = blockIdx.x * ch;
    const int tid = threadIdx.x;

    int tbeg = beg + tid * tch;
    int tend = min(tbeg + tch, min(beg + ch, N));
    int lsum = 0;
    for (int i = tbeg; i < tend; ++i) lsum += cnt[i];

    __shared__ int s[256];
    s[tid] = lsum;
    __syncthreads();
    for (int off = 1; off < 256; off <<= 1) {
        int v = (tid >= off) ? s[tid - off] : 0;
        __syncthreads();
        s[tid] += v;
        __syncthreads();
    }
    int prefix = bbase[blockIdx.x] + ((tid == 0) ? 0 : s[tid - 1]);
    for (int i = tbeg; i < tend; ++i) {
        int c = cnt[i];
        row_ptr[i] = prefix;
        cursor[i]  = prefix;
        dis[i] = rsqrtf((float)(c + 1));   // +1 self-loop
        prefix += c;
    }
}

// Bucket-fill: col[pos] = src for each edge, pos allocated per-dst cursor.
__global__ __launch_bounds__(256) void fill_kernel(const void* ei, int E, const int* flag,
                                                   int* cursor, int* col) {
    int e = blockIdx.x * 256 + threadIdx.x;
    if (e >= E) return;
    int f = *flag;
    int s = load_idx(ei, f, e);
    int t = load_idx(ei, f, (long long)E + e);
    int pos = atomicAdd(&cursor[t], 1);
    col[pos] = s;
}

// ---------------------------------------------------------------------------
// xws[row] = bf16( (x[row] @ W) * dis[row] )  via mfma_f32_16x16x32_bf16.
// ---------------------------------------------------------------------------
__global__ __launch_bounds__(256) void gemm_mfma(const float* __restrict__ x,
                                                 const short* __restrict__ Wp,
                                                 const float* __restrict__ dis,
                                                 short* __restrict__ xws, int N) {
    const int tid = threadIdx.x;
    const int wave = tid >> 6;
    const int lane = tid & 63;
    const int lmod = lane & 15;
    const int lgrp = lane >> 4;
    const int rowbase = blockIdx.x * 64 + wave * 16;
    const int arow = rowbase + lmod;
    const bool aok = arow < N;

    f32x4 acc[8];
#pragma unroll
    for (int i = 0; i < 8; ++i) acc[i] = (f32x4){0.f, 0.f, 0.f, 0.f};

#pragma unroll
    for (int ks = 0; ks < 4; ++ks) {
        const int kbase = ks * 32 + lgrp * 8;
        bf16x8 afrag;
        if (aok) {
            const float4 a0 = *(const float4*)&x[(size_t)arow * DD + kbase];
            const float4 a1 = *(const float4*)&x[(size_t)arow * DD + kbase + 4];
            afrag[0] = f2bf(a0.x); afrag[1] = f2bf(a0.y);
            afrag[2] = f2bf(a0.z); afrag[3] = f2bf(a0.w);
            afrag[4] = f2bf(a1.x); afrag[5] = f2bf(a1.y);
            afrag[6] = f2bf(a1.z); afrag[7] = f2bf(a1.w);
        } else {
#pragma unroll
            for (int i = 0; i < 8; ++i) afrag[i] = 0;
        }
#pragma unroll
        for (int nt = 0; nt < 8; ++nt) {
            bf16x8 bfrag = *(const bf16x8*)&Wp[(nt * 16 + lmod) * DD + kbase];
            acc[nt] = __builtin_amdgcn_mfma_f32_16x16x32_bf16(afrag, bfrag, acc[nt], 0, 0, 0);
        }
    }

#pragma unroll
    for (int r = 0; r < 4; ++r) {
        const int row = rowbase + lgrp * 4 + r;
        if (row < N) {
            const float ds = dis[row];
#pragma unroll
            for (int nt = 0; nt < 8; ++nt)
                xws[(size_t)row * DD + nt * 16 + lmod] = f2bf(acc[nt][r] * ds);
        }
    }
}

// ---------------------------------------------------------------------------
// Pull-gather (bf16 rows): out[t] = x[t] + b + dis[t]*(xws[t] + sum xws[col_e])
// Half-wave per node; 4x-unrolled edge loop, 4 gathers in flight, dual
// accumulator sets to break the fadd dependency chain.
// ---------------------------------------------------------------------------
__global__ __launch_bounds__(256) void gather_kernel(const short* __restrict__ xws,
                                                     const float* __restrict__ x,
                                                     const float* __restrict__ b,
                                                     const float* __restrict__ dis,
                                                     const int* __restrict__ row_ptr,
                                                     const int* __restrict__ col,
                                                     float* __restrict__ out, int N) {
    const int node = blockIdx.x * 8 + (threadIdx.x >> 5);
    if (node >= N) return;
    const int lane = threadIdx.x & 31;
    const ushort4* xw4 = (const ushort4*)xws;
    const size_t base = (size_t)node * 32 + lane;

    // independent loads issued up front to overlap with the gather loop
    const float  d  = dis[node];
    const float4 xv = ((const float4*)x)[base];
    const float4 bv = ((const float4*)b)[lane];

    ushort4 sv = xw4[base];                       // self-loop term (pre-scaled)
    float a0 = bf2f(sv.x), a1 = bf2f(sv.y), a2 = bf2f(sv.z), a3 = bf2f(sv.w);
    float c0 = 0.f, c1 = 0.f, c2 = 0.f, c3 = 0.f;

    const int beg = row_ptr[node], end = row_ptr[node + 1];
    int i = beg;
    for (; i + 4 <= end; i += 4) {
        const int s0 = col[i], s1 = col[i + 1], s2 = col[i + 2], s3 = col[i + 3];
        const ushort4 v0 = xw4[(size_t)s0 * 32 + lane];
        const ushort4 v1 = xw4[(size_t)s1 * 32 + lane];
        const ushort4 v2 = xw4[(size_t)s2 * 32 + lane];
        const ushort4 v3 = xw4[(size_t)s3 * 32 + lane];
        a0 += bf2f(v0.x); a1 += bf2f(v0.y); a2 += bf2f(v0.z); a3 += bf2f(v0.w);
        c0 += bf2f(v1.x); c1 += bf2f(v1.y); c2 += bf2f(v1.z); c3 += bf2f(v1.w);
        a0 += bf2f(v2.x); a1 += bf2f(v2.y); a2 += bf2f(v2.z); a3 += bf2f(v2.w);
        c0 += bf2f(v3.x); c1 += bf2f(v3.y); c2 += bf2f(v3.z); c3 += bf2f(v3.w);
    }
    for (; i < end; ++i) {
        const ushort4 v = xw4[(size_t)col[i] * 32 + lane];
        a0 += bf2f(v.x); a1 += bf2f(v.y); a2 += bf2f(v.z); a3 += bf2f(v.w);
    }
    a0 += c0; a1 += c1; a2 += c2; a3 += c3;

    float4 o;
    o.x = xv.x + bv.x + d * a0;
    o.y = xv.y + bv.y + d * a1;
    o.z = xv.z + bv.z + d * a2;
    o.w = xv.w + bv.w + d * a3;
    ((float4*)out)[base] = o;
}

extern "C" void kernel_launch(void* const* d_in, const int* in_sizes, int n_in,
                              void* d_out, int out_size, void* d_ws, size_t ws_size,
                              hipStream_t stream) {
    const float* x  = (const float*)d_in[0];
    const void*  ei = d_in[1];
    const float* W  = (const float*)d_in[2];
    const float* b  = (const float*)d_in[3];
    float* out = (float*)d_out;

    const int N = in_sizes[0] / DD;
    const int E = in_sizes[1] / 2;

    // Workspace: flag | bsum | bbase | cnt | dis | row_ptr | cursor | col | Wp | xws
    char* ws = (char*)d_ws;
    int*   flag    = (int*)ws;
    int*   bsum    = (int*)(ws + 256);
    int*   bbase   = bsum + SB;
    int*   cnt     = bbase + SB;
    float* dis     = (float*)(cnt + N);
    int*   row_ptr = (int*)(dis + N);
    int*   cursor  = row_ptr + (N + 1);
    int*   col     = cursor + N;
    size_t off = 256 + (size_t)SB * 8 + (size_t)N * 16 + 4 + (size_t)E * 4;
    off = (off + 255) & ~(size_t)255;
    short* Wp  = (short*)(ws + off);
    off += (size_t)DD * DD * 2;               // 32 KB, keeps 256 alignment
    short* xws = (short*)(ws + off);

    hipMemsetAsync(cnt, 0, (size_t)N * 4, stream);
    count_kernel<<<(E + 255) / 256, 256, 0, stream>>>(ei, E, flag, cnt);
    scan_part<<<SB, 256, 0, stream>>>(cnt, N, bsum, W, Wp);
    scan_mid<<<1, SB, 0, stream>>>(bsum, bbase, row_ptr, N);
    scan_final<<<SB, 256, 0, stream>>>(cnt, N, bbase, row_ptr, cursor, dis);
    gemm_mfma<<<(N + 63) / 64, 256, 0, stream>>>(x, Wp, dis, xws, N);
    fill_kernel<<<(E + 255) / 256, 256, 0, stream>>>(ei, E, flag, cursor, col);
    gather_kernel<<<(N + 7) / 8, 256, 0, stream>>>(xws, x, b, dis, row_ptr, col, out, N);
}